// Round 8
// baseline (336.750 us; speedup 1.0000x reference)
//
#include <hip/hip_runtime.h>

// ===== R8: wave-private domains — ZERO barriers, ZERO LDS (sync-elimination
// test), REPEAT=3 diagnostic =====
// R5-R7: write rate pinned at 4.7-4.8 TB/s (vs fill 6.9) across barrier type,
// occupancy, exchange period, store balance. Common element: per-step
// 4-wave barrier rendezvous. This round: sync domain = ONE wave (64 lanes =
// 8 d4-lanes x 8 q-groups, K=15 f4 rows/lane, window 120, owned T=16,
// halo 52>=50). Boundary exchange = 2 x __shfl(lane+-8), wave-synchronous,
// consumed last in each step (edge rows updated after middle rows) so the
// ds_bpermute latency hides under 13 independent row stencils. 4096
// independent waves (4/SIMD, 0 LDS, ~100 VGPR) stream stores with no
// rendezvous anywhere. Cost: redundancy 7.5x -> VALUBusy ~60-70% predicted,
// still under the 1.22us/step store floor.

namespace {

typedef float f4 __attribute__((ext_vector_type(4)));

constexpr int   REPEAT  = 3;    // diagnostic replication (drop when tuned)
constexpr int   B       = 8;
constexpr int   N       = 2048;
constexpr int   D4      = 32;   // 128 floats = 32 f4 per row
constexpr int   STEPS   = 50;
constexpr float ALPHA   = 0.1f;

constexpr int   LANES_D = 8;            // d4 lanes per domain (128B segs)
constexpr int   GQ      = 8;            // q-groups per wave
constexpr int   K       = 15;           // f4 rows per lane
constexpr int   WIN     = GQ * K;       // 120 window rows
constexpr int   T       = 16;           // owned rows per domain
constexpr int   HALO    = (WIN - T) / 2; // 52 >= 50
constexpr int   CHUNKS  = N / T;        // 128
constexpr int   SPLITD  = D4 / LANES_D; // 4 d-quarters
// domains = B * CHUNKS * SPLITD = 4096 waves = 4 per SIMD

__device__ __forceinline__ f4 stencil(const f4 p, const f4 c, const f4 n) {
    return c + ALPHA * (p + n - 2.0f * c);
}

__device__ __forceinline__ f4 shfl_f4(f4 v, int src) {
    f4 r;
    r.x = __shfl(v.x, src, 64);
    r.y = __shfl(v.y, src, 64);
    r.z = __shfl(v.z, src, 64);
    r.w = __shfl(v.w, src, 64);
    return r;
}

__global__ __launch_bounds__(256, 4) void diffusion_wave(
        const f4* __restrict__ in4, f4* __restrict__ out4) {
    const int tid  = threadIdx.x;
    const int lane = tid & 63;
    const int wavi = tid >> 6;            // wave within block (independent)
    const int d4l  = lane & (LANES_D - 1);
    const int g    = lane >> 3;           // q-group 0..7

    const int did   = blockIdx.x * 4 + wavi;       // domain id 0..4095
    const int dh    = did & (SPLITD - 1);          // d-quarter
    const int chunk = (did >> 2) & (CHUNKS - 1);   // n-chunk
    const int b     = did >> 9;                    // batch
    const int n0    = chunk * T;
    const int d4g   = dh * LANES_D + d4l;          // global f4 column

    const int rbase = g * K;

    for (int rep = 0; rep < REPEAT; ++rep) {
        f4 s[K];
        // Load window rows with wraparound (all real rows -> valid at t=0).
#pragma unroll
        for (int i = 0; i < K; ++i) {
            const int ng = (n0 + rbase + i - HALO + 2 * N) & (N - 1);
            s[i] = in4[(b * N + ng) * D4 + d4g];
        }

        // out[0] = initial state (owned rows only)
#pragma unroll
        for (int i = 0; i < K; ++i) {
            const int r = rbase + i;
            if (r >= HALO && r < HALO + T) {
                __builtin_nontemporal_store(
                    s[i], &out4[(b * N + (n0 + r - HALO)) * D4 + d4g]);
            }
        }

        for (int k = 1; k <= STEPS; ++k) {
            // Neighbor boundary rows (pre-update values): wave-synchronous
            // shuffles, no barrier. Consumed at the END of the step.
            f4 bl = shfl_f4(s[K - 1], (lane - LANES_D) & 63);
            f4 bh = shfl_f4(s[0],     (lane + LANES_D) & 63);
            if (g == 0)      bl = (f4)(0.f);   // window edge: fake neighbor
            if (g == GQ - 1) bh = (f4)(0.f);   // creep < HALO over 50 steps

            const int outbase = (k * B + b) * N;
            const f4 old0 = s[0];
            const f4 old1 = s[1];
            f4 prev = old0;
            // Middle rows 1..K-2 (independent of shuffle results).
#pragma unroll
            for (int i = 1; i <= K - 2; ++i) {
                const f4 cur = s[i];
                const f4 nxt = (i < K - 2) ? s[i + 1] : s[K - 1];
                s[i] = stencil(prev, cur, nxt);
                prev = cur;
                const int r = rbase + i;
                if (r >= HALO && r < HALO + T) {
                    __builtin_nontemporal_store(
                        s[i],
                        &out4[(outbase + (n0 + r - HALO)) * D4 + d4g]);
                }
            }
            // Edge rows last: shuffle latency fully hidden. prev = old s[K-2].
            s[0] = stencil(bl, old0, old1);
            {
                const int r = rbase;
                if (r >= HALO && r < HALO + T) {
                    __builtin_nontemporal_store(
                        s[0],
                        &out4[(outbase + (n0 + r - HALO)) * D4 + d4g]);
                }
            }
            s[K - 1] = stencil(prev, s[K - 1], bh);
            {
                const int r = rbase + K - 1;
                if (r >= HALO && r < HALO + T) {
                    __builtin_nontemporal_store(
                        s[K - 1],
                        &out4[(outbase + (n0 + r - HALO)) * D4 + d4g]);
                }
            }
        }
    }
}

}  // namespace

extern "C" void kernel_launch(void* const* d_in, const int* in_sizes, int n_in,
                              void* d_out, int out_size, void* d_ws, size_t ws_size,
                              hipStream_t stream) {
    const f4* in4  = reinterpret_cast<const f4*>(d_in[0]);
    f4*       out4 = reinterpret_cast<f4*>(d_out);

    dim3 grid(1024);   // 4096 wave-domains / 4 waves per block
    dim3 block(256);
    diffusion_wave<<<grid, block, 0, stream>>>(in4, out4);
}

// Round 9
// 252.222 us; speedup vs baseline: 1.3351x; 1.3351x over previous
//
#include <hip/hip_runtime.h>

// ===== R9: R5 + block phase-stagger (global-oscillation test), REPEAT=3 =====
// Evidence: write rate pinned 4.7-4.8 TB/s across barrier style / occupancy /
// exchange period / store balance / zero-sync; R6 proved >=6.0 TB/s total
// bytes sustainable. Theory: all blocks phase-locked (identical per-step
// work, simultaneous launch) -> chip-wide store-lull oscillation; per-step
// exchange residue (~0.45us) starves the write pipe -> duty ~70%.
// Test: one-time per-block phase delay (hash of blockIdx -> 0..3 quarter-step
// sleeps) so co-resident blocks interleave store windows. Kernel body is
// byte-identical to R5 (84.7us/rep best): K=9, per-step LDS exchange, one
// raw barrier + lgkmcnt-only wait, nontemporal in-loop stores.

namespace {

typedef float f4 __attribute__((ext_vector_type(4)));

constexpr int   REPEAT = 3;     // diagnostic replication (drop when tuned)
constexpr int   B      = 8;
constexpr int   N      = 2048;
constexpr int   D4     = 32;    // 128 floats = 32 f4 per row (global)
constexpr int   SPLITD = 2;
constexpr int   D4L    = D4 / SPLITD;   // 16 f4 lanes per block
constexpr int   STEPS  = 50;
constexpr float ALPHA  = 0.1f;
constexpr int   T      = 32;    // owned rows per block
constexpr int   QG     = 16;    // q-groups (256 thr / 16 lanes)
constexpr int   K      = 9;     // rows per thread
constexpr int   R      = QG * K;        // 144 staged rows
constexpr int   HALO_L = (R - T) / 2;   // 56 >= 50
constexpr int   CHUNKS = N / T;         // 64

__device__ __forceinline__ f4 stencil(const f4 p, const f4 c, const f4 n) {
    return c + ALPHA * (p + n - 2.0f * c);
}

__global__ __launch_bounds__(QG * D4L, 4) void diffusion_halo(
        const f4* __restrict__ in4, f4* __restrict__ out4) {
    // Phase stagger: hash blockIdx -> 0..3; sleep ph * ~1024 cycles (~0.43us)
    // once at entry. Placement-agnostic decorrelation of step phases.
    {
        const unsigned ph = (blockIdx.x * 2654435761u) >> 30;  // 0..3
        for (unsigned i = 0; i < ph; ++i) __builtin_amdgcn_s_sleep(16);
    }

    const int tid = threadIdx.x;
    const int d4l = tid & (D4L - 1);  // f4 lane within this d-half
    const int q   = tid >> 4;         // row-group 0..15

    const int bid = blockIdx.x;
    const int dh  = bid & (SPLITD - 1);
    const int c   = (bid >> 1) & (CHUNKS - 1);
    const int b   = bid >> 7;
    const int n0  = c * T;
    const int d4g = dh * D4L + d4l;

    // Double-buffered boundary board: one barrier per step.
    __shared__ f4 lo[2][QG][D4L];
    __shared__ f4 hi[2][QG][D4L];

    const int rbase = q * K;

    for (int rep = 0; rep < REPEAT; ++rep) {
        f4 s[K];
        // Load K rows with wraparound: ng = (n0 + r - HALO_L) mod N.
#pragma unroll
        for (int i = 0; i < K; ++i) {
            const int ng = (n0 + rbase + i + (N - HALO_L)) & (N - 1);
            s[i] = in4[(b * N + ng) * D4 + d4g];
        }

        // out[0] = initial state (owned rows only)
#pragma unroll
        for (int i = 0; i < K; ++i) {
            const int r = rbase + i;
            if (r >= HALO_L && r < HALO_L + T) {
                __builtin_nontemporal_store(
                    s[i], &out4[(b * N + (n0 + r - HALO_L)) * D4 + d4g]);
            }
        }

        for (int k = 1; k <= STEPS; ++k) {
            const int buf = k & 1;
            // Publish old boundary rows of this group.
            lo[buf][q][d4l] = s[0];
            hi[buf][q][d4l] = s[K - 1];
            // LDS ordering only — stores stay in flight across barrier.
            asm volatile("s_waitcnt lgkmcnt(0)" ::: "memory");
            __builtin_amdgcn_s_barrier();
            const f4 bl = (q > 0)      ? hi[buf][q - 1][d4l] : (f4)(0.f);
            const f4 bh = (q < QG - 1) ? lo[buf][q + 1][d4l] : (f4)(0.f);
            // No second barrier: next iter writes buf^1; reuse of buf two
            // steps later is fenced by intervening lgkmcnt(0)+barrier.

            // In-register carry-chain stencil; store owned rows as made.
            const int outbase = (k * B + b) * N;
            f4 prev = bl;
#pragma unroll
            for (int i = 0; i < K; ++i) {
                const f4 cur = s[i];
                f4 nxt = bh;
                if (i + 1 < K) nxt = s[i + 1];
                s[i] = stencil(prev, cur, nxt);
                prev = cur;
                const int r = rbase + i;
                if (r >= HALO_L && r < HALO_L + T) {
                    __builtin_nontemporal_store(
                        s[i],
                        &out4[(outbase + (n0 + r - HALO_L)) * D4 + d4g]);
                }
            }
        }
    }
}

}  // namespace

extern "C" void kernel_launch(void* const* d_in, const int* in_sizes, int n_in,
                              void* d_out, int out_size, void* d_ws, size_t ws_size,
                              hipStream_t stream) {
    const f4* in4  = reinterpret_cast<const f4*>(d_in[0]);
    f4*       out4 = reinterpret_cast<f4*>(d_out);

    dim3 grid(B * CHUNKS * SPLITD);  // 1024 blocks -> 4 per CU
    dim3 block(QG * D4L);            // 256 threads
    diffusion_halo<<<grid, block, 0, stream>>>(in4, out4);
}